// Round 4
// baseline (517.327 us; speedup 1.0000x reference)
//
#include <hip/hip_runtime.h>
#include <stdint.h>

#define S_ROWS 100000
#define NQ     2048
#define M_POS  16
#define VOCABS 32
#define BLOCKS 250    // one co-resident round on 256 CUs (128 KB LDS -> 1 block/CU)
#define RPB    400    // rows per block
#define PASSES 25     // RPB / 16 waves

// full adder / half adder on bit-planes
__device__ __forceinline__ void FA(uint32_t a, uint32_t b, uint32_t c,
                                   uint32_t& s, uint32_t& co) {
    uint32_t x = a ^ b;
    s  = x ^ c;
    co = (a & b) | (x & c);
}
__device__ __forceinline__ void HA(uint32_t a, uint32_t b, uint32_t& s, uint32_t& co) {
    s = a ^ b; co = a & b;
}

// ---------------- fused: stream support, decode in-register, bit-sliced score --
// LDS 128 KB: query-bitmask table[m][v][word] during the main loop, aliased as
// keys[j][wave*64+word] for the cross-wave reduction afterwards.
__global__ __launch_bounds__(1024, 4) void knn_fused(const int* __restrict__ utts,
                                                     const float* __restrict__ support,
                                                     uint32_t* __restrict__ partial) {
    __shared__ uint32_t smem[32768];   // 128 KB

    const int t = threadIdx.x;
    const int c = blockIdx.x;

    // zero table: 32 words/thread as 8x uint4
    #pragma unroll
    for (int i = 0; i < 8; ++i)
        *(uint4*)&smem[t * 4 + i * 4096] = uint4{0u, 0u, 0u, 0u};
    __syncthreads();

    // build table: bit j of table[(m*32+v)*64 + wd] = (utts[m][wd*32+j] == v)
    #pragma unroll
    for (int h = 0; h < 2; ++h) {
        int q  = t + h * 1024;
        int wd = q >> 5, bit = q & 31;
        #pragma unroll
        for (int m = 0; m < M_POS; ++m) {
            int v = utts[m * NQ + q];
            atomicOr(&smem[m * 2048 + v * 64 + wd], 1u << bit);
        }
    }
    __syncthreads();

    const int wave = t >> 6;
    const int lane = t & 63;

    uint32_t cp0=0,cp1=0,cp2=0,cp3=0,cp4=0;   // current-max count planes (32 queries)
    uint32_t k0p=0,k1p=0,k2p=0,k3p=0,k4p=0;   // winning-pass planes

    // wave v, pass p handles global row c*400 + p*16 + v
    const float* rowbase = support + ((size_t)c * RPB + wave) * 512 + lane * 8;

    #pragma unroll
    for (int p = 0; p < PASSES; ++p) {
        // ---- decode this wave's row: lane reads 8 floats, quad-reduce to token*8
        const float4* rp = (const float4*)(rowbase + (size_t)p * 16 * 512);
        float4 f0 = rp[0];
        float4 f1 = rp[1];
        float base = (float)((lane & 3) * 64);
        float v = f0.x * (base + 0.f)  + f0.y * (base + 8.f)  + f0.z * (base + 16.f) + f0.w * (base + 24.f)
                + f1.x * (base + 32.f) + f1.y * (base + 40.f) + f1.z * (base + 48.f) + f1.w * (base + 56.f);
        v += __shfl_xor(v, 1);
        v += __shfl_xor(v, 2);
        int tok8 = (int)(v + 0.5f);           // token*8 for position lane>>2

        // ---- gather 16 query-bitmask words for this row; lane = query word
        uint32_t b[16];
        #pragma unroll
        for (int m = 0; m < 16; ++m) {
            uint32_t tm = (uint32_t)__shfl(tok8, 4 * m);   // wave-uniform -> readlane
            b[m] = smem[m * 2048 + tm * 8 + lane];         // bank = lane&31: clean
        }

        // ---- CSA tree: 16 one-bit planes -> 5-bit count planes n0..n4
        uint32_t s10,s11,s12,s13,s14, c10,c11,c12,c13,c14;
        FA(b[0],b[1],b[2],   s10,c10);
        FA(b[3],b[4],b[5],   s11,c11);
        FA(b[6],b[7],b[8],   s12,c12);
        FA(b[9],b[10],b[11], s13,c13);
        FA(b[12],b[13],b[14],s14,c14);
        uint32_t s2a,c2a,s2b,c2b;
        FA(s10,s11,s12, s2a,c2a);
        FA(s13,s14,b[15], s2b,c2b);
        uint32_t n0,h0;  HA(s2a,s2b, n0,h0);
        uint32_t u,cu,vv,cv,x2,cx,n1,cy;
        FA(c10,c11,c12, u,cu);
        FA(c13,c14,c2a, vv,cv);
        FA(u,vv,c2b,    x2,cx);
        HA(x2,h0,       n1,cy);
        uint32_t y4,cz,n2,cw,n3,n4;
        FA(cu,cv,cx, y4,cz);
        HA(y4,cy,    n2,cw);
        HA(cz,cw,    n3,n4);

        // ---- gt = (new count > current max), bit-sliced 5-bit compare
        uint32_t eq = ~(n4 ^ cp4);
        uint32_t gt = n4 & ~cp4;
        gt |= eq & (n3 & ~cp3);  eq &= ~(n3 ^ cp3);
        gt |= eq & (n2 & ~cp2);  eq &= ~(n2 ^ cp2);
        gt |= eq & (n1 & ~cp1);  eq &= ~(n1 ^ cp1);
        gt |= eq & (n0 & ~cp0);

        uint32_t ng = ~gt;
        cp0 = (gt & n0) | (ng & cp0);
        cp1 = (gt & n1) | (ng & cp1);
        cp2 = (gt & n2) | (ng & cp2);
        cp3 = (gt & n3) | (ng & cp3);
        cp4 = (gt & n4) | (ng & cp4);
        // p is a compile-time literal (full unroll)
        k0p = ( p       & 1) ? (k0p & ng) | gt : (k0p & ng);
        k1p = ((p >> 1) & 1) ? (k1p & ng) | gt : (k1p & ng);
        k2p = ((p >> 2) & 1) ? (k2p & ng) | gt : (k2p & ng);
        k3p = ((p >> 3) & 1) ? (k3p & ng) | gt : (k3p & ng);
        k4p = ((p >> 4) & 1) ? (k4p & ng) | gt : (k4p & ng);
    }

    __syncthreads();   // table reads done; alias smem as keys[j][wave*64+lane]

    // extract packed keys: key = (cnt<<17) | (0x1FFFF - row), row = c*400 + p*16 + wave
    {
        uint32_t C0 = 0x1FFFFu - (uint32_t)(c * RPB + wave);
        #pragma unroll 1
        for (int j = 0; j < 32; ++j) {
            uint32_t cnt = ((cp0>>j)&1u) | (((cp1>>j)&1u)<<1) | (((cp2>>j)&1u)<<2)
                         | (((cp3>>j)&1u)<<3) | (((cp4>>j)&1u)<<4);
            uint32_t pw  = ((k0p>>j)&1u) | (((k1p>>j)&1u)<<1) | (((k2p>>j)&1u)<<2)
                         | (((k3p>>j)&1u)<<3) | (((k4p>>j)&1u)<<4);
            smem[j * 1024 + t] = (cnt << 17) + C0 - (pw << 4);
        }
    }
    __syncthreads();

    // cross-wave reduce: query q = w*32 + j; max over 16 waves
    #pragma unroll
    for (int h = 0; h < 2; ++h) {
        int j = (t >> 6) + h * 16;
        int w = t & 63;
        uint32_t best = 0;
        #pragma unroll
        for (int v2 = 0; v2 < 16; ++v2) {
            uint32_t x = smem[j * 1024 + v2 * 64 + w];   // bank = w&31: 2-way, free
            best = best > x ? best : x;
        }
        partial[(size_t)c * NQ + w * 32 + j] = best;
    }
}

// ---------------- final reduce over blocks + one-hot output --------------------
__global__ __launch_bounds__(256) void knn_reduce_out(const uint32_t* __restrict__ partial,
                                                      const int* __restrict__ meanings,
                                                      float* __restrict__ out) {
    int q = blockIdx.x * 256 + threadIdx.x;
    if (q >= NQ) return;
    uint32_t best = 0;
    #pragma unroll 5
    for (int c = 0; c < BLOCKS; ++c) {
        uint32_t v = partial[(size_t)c * NQ + q];
        best = best > v ? best : v;
    }
    int idx = 0x1FFFF - (int)(best & 0x1FFFFu);
    float* o = out + (size_t)q * 50;
    #pragma unroll
    for (int tt = 0; tt < 5; ++tt) {
        int mv = meanings[(size_t)idx * 5 + tt];
        #pragma unroll
        for (int mm = 0; mm < 10; ++mm) o[tt * 10 + mm] = (mm == mv) ? 1.0f : 0.0f;
    }
}

extern "C" void kernel_launch(void* const* d_in, const int* in_sizes, int n_in,
                              void* d_out, int out_size, void* d_ws, size_t ws_size,
                              hipStream_t stream) {
    const int*   utts     = (const int*)d_in[0];     // [16, 2048]
    const float* support  = (const float*)d_in[1];   // [100000, 512]
    const int*   meanings = (const int*)d_in[2];     // [100000, 5]
    float* out = (float*)d_out;                      // [2048, 5, 10]

    uint32_t* partial = (uint32_t*)d_ws;             // 250*2048*4 = 2 MB

    knn_fused<<<BLOCKS, 1024, 0, stream>>>(utts, support, partial);
    knn_reduce_out<<<NQ / 256, 256, 0, stream>>>(partial, meanings, out);
}

// Round 5
// 327.261 us; speedup vs baseline: 1.5808x; 1.5808x over previous
//
#include <hip/hip_runtime.h>
#include <stdint.h>

#define S_ROWS 100000
#define NQ     2048
#define M_POS  16
#define BLOCKS 250    // 1 block/CU (128 KB LDS), single co-resident round
#define RPB    400    // rows per block
#define WAVES  8
#define PASSES 50     // RPB / WAVES

// full adder / half adder on bit-planes
__device__ __forceinline__ void FA(uint32_t a, uint32_t b, uint32_t c,
                                   uint32_t& s, uint32_t& co) {
    uint32_t x = a ^ b;
    s  = x ^ c;
    co = (a & b) | (x & c);
}
__device__ __forceinline__ void HA(uint32_t a, uint32_t b, uint32_t& s, uint32_t& co) {
    s = a ^ b; co = a & b;
}

// ---------------- kernel A: build query-bitmask table in global memory --------
// Owner-computes: thread tau = (m, wd) builds all 32 v-words for its 32 queries.
// No atomics, no zero-init needed (every word written exactly once).
__global__ __launch_bounds__(1024) void knn_build(const int* __restrict__ utts,
                                                  uint32_t* __restrict__ gtable) {
    int tau = threadIdx.x;        // 1024 = 16 m * 64 wd
    int m  = tau >> 6;
    int wd = tau & 63;
    int x[32];
    #pragma unroll
    for (int j = 0; j < 32; ++j) x[j] = utts[m * NQ + wd * 32 + j];
    #pragma unroll
    for (int v = 0; v < 32; ++v) {
        uint32_t w = 0;
        #pragma unroll
        for (int j = 0; j < 32; ++j) w |= (uint32_t)(x[j] == v) << j;
        gtable[m * 2048 + v * 64 + wd] = w;
    }
}

// ---------------- kernel B: fused stream + decode + bit-sliced score ----------
// LDS 128 KB: table[m][v][wd] during main loop, aliased as keys[j][t] after.
__global__ __launch_bounds__(512, 2) void knn_fused(const uint32_t* __restrict__ gtable,
                                                    const float* __restrict__ support,
                                                    uint32_t* __restrict__ partial) {
    __shared__ uint32_t smem[32768];   // 128 KB

    const int t = threadIdx.x;
    const int c = blockIdx.x;

    // load prebuilt table, fully coalesced: 16 x uint4 per thread
    #pragma unroll
    for (int i = 0; i < 16; ++i)
        *(uint4*)&smem[t * 4 + i * 2048] = *(const uint4*)&gtable[t * 4 + i * 2048];
    __syncthreads();

    const int wave = t >> 6;
    const int lane = t & 63;

    uint32_t cp0=0,cp1=0,cp2=0,cp3=0,cp4=0;             // current-max count planes
    uint32_t k0p=0,k1p=0,k2p=0,k3p=0,k4p=0,k5p=0;       // winning-pass planes (6b)

    // wave w, pass p handles row c*400 + p*8 + w
    const float* rowbase = support + ((size_t)c * RPB + wave) * 512 + lane * 8;
    const float base = (float)((lane & 3) * 64);

    // 2-deep software pipeline: 4 float4 buffers, rotate by 2
    const float4* rp0 = (const float4*)(rowbase);
    const float4* rp1 = (const float4*)(rowbase + 4096);
    float4 A0 = rp0[0], B0 = rp0[1];
    float4 A1 = rp1[0], B1 = rp1[1];

    #pragma unroll 1
    for (int p = 0; p < PASSES; p += 2) {
        float4 A2, B2, A3, B3;
        if (p + 2 < PASSES) {
            const float4* rp = (const float4*)(rowbase + (size_t)(p + 2) * 4096);
            A2 = rp[0]; B2 = rp[1];
        }
        if (p + 3 < PASSES) {
            const float4* rp = (const float4*)(rowbase + (size_t)(p + 3) * 4096);
            A3 = rp[0]; B3 = rp[1];
        }

        #pragma unroll
        for (int half = 0; half < 2; ++half) {
            float4 fa = half ? A1 : A0;
            float4 fb = half ? B1 : B0;
            int    pp = p + half;

            // decode: quad-reduce one-hot dot -> token*8 for position lane>>2
            float v = fa.x * (base + 0.f)  + fa.y * (base + 8.f)  + fa.z * (base + 16.f) + fa.w * (base + 24.f)
                    + fb.x * (base + 32.f) + fb.y * (base + 40.f) + fb.z * (base + 48.f) + fb.w * (base + 56.f);
            v += __shfl_xor(v, 1);
            v += __shfl_xor(v, 2);
            int tok8 = (int)(v + 0.5f);

            // gather 16 query-bitmask words; lane = query word (bank clean)
            uint32_t b[16];
            #pragma unroll
            for (int m = 0; m < 16; ++m) {
                uint32_t tm = (uint32_t)__shfl(tok8, 4 * m);   // wave-uniform
                b[m] = smem[m * 2048 + tm * 8 + lane];
            }

            // CSA tree: 16 one-bit planes -> 5-bit count planes n0..n4
            uint32_t s10,s11,s12,s13,s14, c10,c11,c12,c13,c14;
            FA(b[0],b[1],b[2],   s10,c10);
            FA(b[3],b[4],b[5],   s11,c11);
            FA(b[6],b[7],b[8],   s12,c12);
            FA(b[9],b[10],b[11], s13,c13);
            FA(b[12],b[13],b[14],s14,c14);
            uint32_t s2a,c2a,s2b,c2b;
            FA(s10,s11,s12, s2a,c2a);
            FA(s13,s14,b[15], s2b,c2b);
            uint32_t n0,h0;  HA(s2a,s2b, n0,h0);
            uint32_t u,cu,vv,cv,x2,cx,n1,cy;
            FA(c10,c11,c12, u,cu);
            FA(c13,c14,c2a, vv,cv);
            FA(u,vv,c2b,    x2,cx);
            HA(x2,h0,       n1,cy);
            uint32_t y4,cz,n2,cw,n3,n4;
            FA(cu,cv,cx, y4,cz);
            HA(y4,cy,    n2,cw);
            HA(cz,cw,    n3,n4);

            // gt = (new count > current max), bit-sliced 5-bit compare
            uint32_t eq = ~(n4 ^ cp4);
            uint32_t gt = n4 & ~cp4;
            gt |= eq & (n3 & ~cp3);  eq &= ~(n3 ^ cp3);
            gt |= eq & (n2 & ~cp2);  eq &= ~(n2 ^ cp2);
            gt |= eq & (n1 & ~cp1);  eq &= ~(n1 ^ cp1);
            gt |= eq & (n0 & ~cp0);

            uint32_t ng = ~gt;
            cp0 = (gt & n0) | (ng & cp0);
            cp1 = (gt & n1) | (ng & cp1);
            cp2 = (gt & n2) | (ng & cp2);
            cp3 = (gt & n3) | (ng & cp3);
            cp4 = (gt & n4) | (ng & cp4);
            uint32_t pu = (uint32_t)pp;
            uint32_t m0 = 0u - ( pu       & 1u);
            uint32_t m1 = 0u - ((pu >> 1) & 1u);
            uint32_t m2 = 0u - ((pu >> 2) & 1u);
            uint32_t m3 = 0u - ((pu >> 3) & 1u);
            uint32_t m4 = 0u - ((pu >> 4) & 1u);
            uint32_t m5 = 0u - ((pu >> 5) & 1u);
            k0p = (gt & m0) | (ng & k0p);
            k1p = (gt & m1) | (ng & k1p);
            k2p = (gt & m2) | (ng & k2p);
            k3p = (gt & m3) | (ng & k3p);
            k4p = (gt & m4) | (ng & k4p);
            k5p = (gt & m5) | (ng & k5p);
        }
        A0 = A2; B0 = B2; A1 = A3; B1 = B3;
    }

    __syncthreads();   // all table gathers done; alias smem as keys[j][t]

    // extract packed keys: key = (cnt<<17) | (0x1FFFF - row), row = c*400 + pw*8 + wave
    {
        uint32_t C0 = 0x1FFFFu - (uint32_t)(c * RPB + wave);
        #pragma unroll 1
        for (int j = 0; j < 32; ++j) {
            uint32_t cnt = ((cp0>>j)&1u) | (((cp1>>j)&1u)<<1) | (((cp2>>j)&1u)<<2)
                         | (((cp3>>j)&1u)<<3) | (((cp4>>j)&1u)<<4);
            uint32_t pw  = ((k0p>>j)&1u) | (((k1p>>j)&1u)<<1) | (((k2p>>j)&1u)<<2)
                         | (((k3p>>j)&1u)<<3) | (((k4p>>j)&1u)<<4) | (((k5p>>j)&1u)<<5);
            smem[j * 512 + t] = (cnt << 17) + C0 - (pw << 3);
        }
    }
    __syncthreads();

    // cross-wave reduce: query q = w*32 + j; max over 8 waves
    #pragma unroll
    for (int h = 0; h < 4; ++h) {
        int j = (t >> 6) + h * 8;
        int w = t & 63;
        uint32_t best = 0;
        #pragma unroll
        for (int v2 = 0; v2 < 8; ++v2) {
            uint32_t x = smem[j * 512 + v2 * 64 + w];   // 2 lanes/bank: free
            best = best > x ? best : x;
        }
        partial[(size_t)c * NQ + w * 32 + j] = best;
    }
}

// ---------------- final reduce over blocks + one-hot output --------------------
__global__ __launch_bounds__(256) void knn_reduce_out(const uint32_t* __restrict__ partial,
                                                      const int* __restrict__ meanings,
                                                      float* __restrict__ out) {
    int q = blockIdx.x * 256 + threadIdx.x;
    if (q >= NQ) return;
    uint32_t best = 0;
    #pragma unroll 5
    for (int c = 0; c < BLOCKS; ++c) {
        uint32_t v = partial[(size_t)c * NQ + q];
        best = best > v ? best : v;
    }
    int idx = 0x1FFFF - (int)(best & 0x1FFFFu);
    float* o = out + (size_t)q * 50;
    #pragma unroll
    for (int tt = 0; tt < 5; ++tt) {
        int mv = meanings[(size_t)idx * 5 + tt];
        #pragma unroll
        for (int mm = 0; mm < 10; ++mm) o[tt * 10 + mm] = (mm == mv) ? 1.0f : 0.0f;
    }
}

extern "C" void kernel_launch(void* const* d_in, const int* in_sizes, int n_in,
                              void* d_out, int out_size, void* d_ws, size_t ws_size,
                              hipStream_t stream) {
    const int*   utts     = (const int*)d_in[0];     // [16, 2048]
    const float* support  = (const float*)d_in[1];   // [100000, 512]
    const int*   meanings = (const int*)d_in[2];     // [100000, 5]
    float* out = (float*)d_out;                      // [2048, 5, 10]

    uint32_t* gtable  = (uint32_t*)d_ws;                             // 128 KB
    uint32_t* partial = (uint32_t*)((char*)d_ws + 32768 * 4);        // 2 MB

    knn_build<<<1, 1024, 0, stream>>>(utts, gtable);
    knn_fused<<<BLOCKS, 512, 0, stream>>>(gtable, support, partial);
    knn_reduce_out<<<NQ / 256, 256, 0, stream>>>(partial, meanings, out);
}